// Round 4
// baseline (164.805 us; speedup 1.0000x reference)
//
#include <hip/hip_runtime.h>
#include <hip/hip_bf16.h>

#define NND   325
#define SEQ   12
#define NT    3900            // 325*12
#define KP    352             // padded j (11 chunks of 32)
#define NC    11              // k-chunks of 32
#define CHUNK_SHORTS 12288    // 384 rows * 32 j  (rows 352..383 are zero pad)
#define MROWS 24              // real gt rows per cheb block (2 g-slices)
#define MP    32              // padded rows (2 m-tiles)

typedef __attribute__((ext_vector_type(8))) short short8;
typedef __attribute__((ext_vector_type(4))) float floatx4;

static __device__ __forceinline__ unsigned short f2bf(float f) {
    unsigned int u = __float_as_uint(f);
    unsigned int r = (u + 0x7fffu + ((u >> 16) & 1u)) >> 16;  // RNE
    return (unsigned short)r;
}

// A-image index (shorts): [MP][KP], 16B slot XOR-swizzled by row
static __device__ __forceinline__ int xi(int m, int j) {
    int slot = (j >> 3) ^ ((m >> 1) & 3);
    return m * KP + slot * 8 + (j & 7);
}
// mix-kernel swizzle (row stride 384 B) — unchanged from round 3
static __device__ __forceinline__ int swz(int n) {
    return ((n & 7) ^ ((n >> 3) & 7)) << 4;
}

// ---- setup: d^{-1/2} ----
__global__ void calc_dis(const float* __restrict__ adj, float* __restrict__ dis) {
    int i = blockIdx.x;
    const float* row = adj + (size_t)i * NND;
    float s = 0.f;
    for (int j = threadIdx.x; j < NND; j += 64) s += row[j];
    for (int o = 32; o; o >>= 1) s += __shfl_down(s, o);
    if (threadIdx.x == 0) dis[i] = (s > 0.f) ? rsqrtf(s) : 0.f;
}

// ---- setup: L as chunk-major pre-swizzled bf16 blobs [c][n<384][32] ----
__global__ void build_L2(const float* __restrict__ adj, const float* __restrict__ dis,
                         unsigned short* __restrict__ Lg2) {
    int s = blockIdx.x * 256 + threadIdx.x;
    if (s >= NC * CHUNK_SHORTS) return;
    int c = s / CHUNK_SHORTS, r = s - c * CHUNK_SHORTS;
    int n = r >> 5, w = r & 31;
    int sl = w >> 3, e = w & 7;
    int j = c * 32 + (sl ^ ((n >> 1) & 3)) * 8 + e;
    float v = 0.f;
    if (n < NND && j < NND) {
        float a = adj[(size_t)n * NND + j];
        v = ((n == j) ? 1.f : 0.f) - dis[n] * a * dis[j];
    }
    Lg2[s] = f2bf(v);
}

// ---- setup: folded weights as swizzled bf16 image A[d][k], k=kind*64+c ----
__global__ void build_wswz(const float* __restrict__ W, unsigned short* __restrict__ wswz) {
    int idx = blockIdx.x * 256 + threadIdx.x;
    if (idx >= 64 * 192) return;
    int d = idx / 192, k = idx - d * 192;
    int kind = k >> 6, c = k & 63;
    float wv = W[kind * 4096 + c * 64 + d];
    float w;
    if (kind == 0)      w = wv - W[2 * 4096 + c * 64 + d];
    else if (kind == 1) w = wv;
    else                w = 2.f * wv;
    int byte = d * 384 + ((2 * k) ^ swz(d));
    wswz[byte >> 1] = f2bf(w);
}

// ---- Chebyshev double L-apply, high-TLP version.
// Block: 24 gt-rows (2 g-slices), 256 threads, 68 KB LDS -> 2 blocks/CU.
// GEMM1: Y[m,n] = sum_j X[m,j] L[n,j]; GEMM2: Z = Y * L. Single L-chunk buffer.
__global__ __launch_bounds__(256, 2) void cheb_mfma(
        const float* __restrict__ x,
        const unsigned short* __restrict__ Lg2,
        unsigned short* __restrict__ Yg,
        unsigned short* __restrict__ Zg) {
    __shared__ __align__(16) unsigned short Xs[MP * KP];      // 22528 B
    __shared__ __align__(16) unsigned short Ys[MP * KP];      // 22528 B
    __shared__ __align__(16) unsigned short Lb[CHUNK_SHORTS]; // 24576 B

    const int tid = threadIdx.x;
    int bid = blockIdx.x;
    bid = (bid & 7) * 256 + (bid >> 3);       // XCD swizzle (2048 = 8*256)
    const int g0 = bid * 2;

    const int l  = tid & 63;
    const int w  = tid >> 6;
    const int lm = l & 15, lg = l >> 4;
    const int mt = w & 1;                     // m-tile (0..1)
    const int nh = w >> 1;                    // n-half (0..1), 11 n-tiles each

    auto loadChunk = [&](int c) {
        const short8* src = (const short8*)(Lg2 + (size_t)c * CHUNK_SHORTS);
        short8 t0 = src[tid];
        short8 t1 = src[tid + 256];
        short8 t2 = src[tid + 512];
        short8 t3 = src[tid + 768];
        short8 t4 = src[tid + 1024];
        short8 t5 = src[tid + 1280];
        *(short8*)&Lb[(tid       ) * 8] = t0;
        *(short8*)&Lb[(tid +  256) * 8] = t1;
        *(short8*)&Lb[(tid +  512) * 8] = t2;
        *(short8*)&Lb[(tid +  768) * 8] = t3;
        *(short8*)&Lb[(tid + 1024) * 8] = t4;
        *(short8*)&Lb[(tid + 1280) * 8] = t5;
    };

    floatx4 acc[11];

    auto zero_acc = [&]() {
        #pragma unroll
        for (int i = 0; i < 11; ++i) acc[i] = (floatx4){0.f, 0.f, 0.f, 0.f};
    };

    auto compute = [&](const unsigned short* Aimg, int c) {
        const int m = mt * 16 + lm;
        const int aslot = (c * 4 + lg) ^ ((m >> 1) & 3);
        short8 a = *(const short8*)&Aimg[m * KP + aslot * 8];
        #pragma unroll
        for (int ntl = 0; ntl < 11; ++ntl) {
            int n = nh * 176 + ntl * 16 + lm;
            int sl = lg ^ ((n >> 1) & 3);
            short8 b = *(const short8*)&Lb[n * 32 + sl * 8];
            acc[ntl] = __builtin_amdgcn_mfma_f32_16x16x32_bf16(a, b, acc[ntl], 0, 0, 0);
        }
    };

    auto store_acc = [&](unsigned short* img) {
        #pragma unroll
        for (int ntl = 0; ntl < 11; ++ntl) {
            int n = nh * 176 + ntl * 16 + lm;
            #pragma unroll
            for (int r = 0; r < 4; ++r) {
                int m = mt * 16 + lg * 4 + r;
                img[xi(m, n)] = f2bf(acc[ntl][r]);
            }
        }
    };

    auto copy_out = [&](const unsigned short* img, unsigned short* dst) {
        for (int i = tid; i < 1950; i += 256) {
            int gl = i / 975;
            int r2 = i - gl * 975;
            int n = r2 / 3;
            int tq = (r2 - n * 3) * 4;
            int m = gl * 12 + tq;
            ushort4 u;
            u.x = img[xi(m + 0, n)];
            u.y = img[xi(m + 1, n)];
            u.z = img[xi(m + 2, n)];
            u.w = img[xi(m + 3, n)];
            *(ushort4*)&dst[(size_t)(g0 + gl) * NT + n * SEQ + tq] = u;
        }
    };

    // ---- prologue: zero pads of Xs, stage X, load chunk 0 ----
    for (int i = tid; i < 352; i += 256) {                    // rows 24..31 full
        int rr = i / 44, u = i - rr * 44;
        *(short8*)&Xs[(MROWS + rr) * KP + u * 8] = (short8)0;
    }
    for (int i = tid; i < 648; i += 256) {                    // rows 0..23, cols 325..351
        int m = i / 27, j = 325 + i - (i / 27) * 27;
        Xs[xi(m, j)] = 0;
    }
    const float4* xb = (const float4*)(x + (size_t)g0 * NT);
    for (int i = tid; i < 1950; i += 256) {
        float4 v = xb[i];
        int f = i * 4;
        int gl = f / NT;
        int rem = f - gl * NT;
        int j = rem / SEQ;
        int t0 = rem - j * SEQ;       // 0,4,8
        int m = gl * SEQ + t0;
        Xs[xi(m + 0, j)] = f2bf(v.x);
        Xs[xi(m + 1, j)] = f2bf(v.y);
        Xs[xi(m + 2, j)] = f2bf(v.z);
        Xs[xi(m + 3, j)] = f2bf(v.w);
    }
    loadChunk(0);
    __syncthreads();

    // ---- GEMM1: Y = X * L ----
    zero_acc();
    for (int c = 0; c < NC; ++c) {
        compute(Xs, c);
        if (c + 1 < NC) {
            __syncthreads();          // all waves done reading Lb
            loadChunk(c + 1);
            __syncthreads();          // chunk ready
        }
    }
    store_acc(Ys);
    __syncthreads();                  // Ys complete, Lb free
    loadChunk(0);
    copy_out(Ys, Yg);
    __syncthreads();

    // ---- GEMM2: Z = Y * L ----
    zero_acc();
    for (int c = 0; c < NC; ++c) {
        compute(Ys, c);
        if (c + 1 < NC) {
            __syncthreads();
            loadChunk(c + 1);
            __syncthreads();
        }
    }
    store_acc(Xs);                    // reuse Xs as Z staging
    __syncthreads();
    copy_out(Xs, Zg);
}

// ---- Phase B: out = A(64x192) x B(192 x 96nt) per (b, nt-tile), MFMA ----
__global__ __launch_bounds__(256) void mix_mfma(
        const float* __restrict__ x,
        const unsigned short* __restrict__ Yg,
        const unsigned short* __restrict__ Zg,
        const unsigned short* __restrict__ wswz,
        const float* __restrict__ bias,
        float* __restrict__ out) {
    __shared__ unsigned short Bl[96 * 192];   // 36864 B swizzled [n][k]
    __shared__ unsigned short Al[64 * 192];   // 24576 B swizzled [d][k]
    const int tid = threadIdx.x;
    int lin = blockIdx.x;
    lin = (lin & 7) * 328 + (lin >> 3);       // XCD swizzle (2624 = 8*328)
    const int b = lin / 41;
    const int nt0 = (lin - b * 41) * 96;
    const bool tail = (nt0 + 96 > NT);

    for (int i = tid; i < 1536; i += 256)
        *(short8*)((char*)Al + i * 16) = *(const short8*)((const char*)wswz + i * 16);

    for (int i = tid; i < 768; i += 256) {
        int r = i / 12, ch = i - r * 12;
        int nt = nt0 + ch * 8;
        const float* sp = x + ((size_t)b * 64 + r) * NT + nt;
        float f[8];
        if (!tail || nt + 8 <= NT) {
            float4 v0 = *(const float4*)sp;
            float4 v1 = *(const float4*)(sp + 4);
            f[0] = v0.x; f[1] = v0.y; f[2] = v0.z; f[3] = v0.w;
            f[4] = v1.x; f[5] = v1.y; f[6] = v1.z; f[7] = v1.w;
        } else {
            #pragma unroll
            for (int jj = 0; jj < 8; ++jj) f[jj] = (nt + jj < NT) ? sp[jj] : 0.f;
        }
        int k2 = 2 * r;
        #pragma unroll
        for (int jj = 0; jj < 8; ++jj) {
            int n = ch * 8 + jj;
            *(unsigned short*)((char*)Bl + n * 384 + (k2 ^ swz(n))) = f2bf(f[jj]);
        }
    }
    for (int i = tid; i < 1536; i += 256) {
        int r = 64 + i / 12, ch = i % 12;
        int nt = nt0 + ch * 8;
        const unsigned short* base = (r < 128) ? Yg : Zg;
        const unsigned short* sp = base + ((size_t)b * 64 + (r & 63)) * NT + nt;
        unsigned short f[8];
        if (!tail || nt + 8 <= NT) {
            ushort4 v0 = *(const ushort4*)sp;
            ushort4 v1 = *(const ushort4*)(sp + 4);
            f[0] = v0.x; f[1] = v0.y; f[2] = v0.z; f[3] = v0.w;
            f[4] = v1.x; f[5] = v1.y; f[6] = v1.z; f[7] = v1.w;
        } else {
            #pragma unroll
            for (int jj = 0; jj < 8; ++jj) f[jj] = (nt + jj < NT) ? sp[jj] : (unsigned short)0;
        }
        int k2 = 2 * r;
        #pragma unroll
        for (int jj = 0; jj < 8; ++jj) {
            int n = ch * 8 + jj;
            *(unsigned short*)((char*)Bl + n * 384 + (k2 ^ swz(n))) = f[jj];
        }
    }
    __syncthreads();

    const int w = __builtin_amdgcn_readfirstlane(tid >> 6);
    const int l = tid & 63;
    const int lm = l & 15, lg = l >> 4;

    floatx4 acc[6];
    #pragma unroll
    for (int i = 0; i < 6; ++i) acc[i] = (floatx4){0.f, 0.f, 0.f, 0.f};

    const int arow = w * 16 + lm;
    const char* Ab = (const char*)Al + arow * 384;
    #pragma unroll
    for (int ks = 0; ks < 6; ++ks) {
        const int k2 = (ks * 32 + lg * 8) * 2;
        short8 a = *(const short8*)(Ab + (k2 ^ swz(arow)));
        #pragma unroll
        for (int ni = 0; ni < 6; ++ni) {
            int n = ni * 16 + lm;
            short8 bb = *(const short8*)((const char*)Bl + n * 384 + (k2 ^ swz(n)));
            acc[ni] = __builtin_amdgcn_mfma_f32_16x16x32_bf16(a, bb, acc[ni], 0, 0, 0);
        }
    }

    float br[4];
    #pragma unroll
    for (int j = 0; j < 4; ++j) br[j] = bias[w * 16 + lg * 4 + j];
    #pragma unroll
    for (int ni = 0; ni < 6; ++ni) {
        int nt = nt0 + ni * 16 + lm;
        if (nt < NT) {
            float* op = out + ((size_t)b * 64 + w * 16 + lg * 4) * NT + nt;
            #pragma unroll
            for (int j = 0; j < 4; ++j) op[(size_t)j * NT] = acc[ni][j] + br[j];
        }
    }
}

extern "C" void kernel_launch(void* const* d_in, const int* in_sizes, int n_in,
                              void* d_out, int out_size, void* d_ws, size_t ws_size,
                              hipStream_t stream) {
    const float* x   = (const float*)d_in[0];
    const float* adj = (const float*)d_in[1];
    const float* W   = (const float*)d_in[2];
    const float* b   = (const float*)d_in[3];
    float* out = (float*)d_out;

    char* ws = (char*)d_ws;
    // layout (bytes):
    //   0        : dis   (325 f32, pad 1312)
    //   1312     : Lg2   (11*12288 bf16 = 270336)
    //   271648   : wswz  (12288 bf16 = 24576)
    //   296224   : Y     (4096*3900 bf16 = 31948800)
    //   32245024 : Z     (31948800) -> end 64193824 (~61.2 MiB)
    float* dis           = (float*)(ws + 0);
    unsigned short* Lg2  = (unsigned short*)(ws + 1312);
    unsigned short* wswz = (unsigned short*)(ws + 271648);
    unsigned short* Yg   = (unsigned short*)(ws + 296224);
    unsigned short* Zg   = (unsigned short*)(ws + 32245024);

    calc_dis<<<NND, 64, 0, stream>>>(adj, dis);
    build_L2<<<(NC * CHUNK_SHORTS + 255) / 256, 256, 0, stream>>>(adj, dis, Lg2);
    build_wswz<<<48, 256, 0, stream>>>(W, wswz);
    cheb_mfma<<<2048, 256, 0, stream>>>(x, Lg2, Yg, Zg);
    mix_mfma<<<2624, 256, 0, stream>>>(x, Yg, Zg, wswz, b, out);
}

// Round 5
// 127.375 us; speedup vs baseline: 1.2939x; 1.2939x over previous
//
#include <hip/hip_runtime.h>
#include <hip/hip_bf16.h>

#define NND   325
#define SEQ   12
#define NT    3900            // 325*12
#define KP    352             // padded j (11 chunks of 32)
#define NC    11              // k-chunks of 32
#define CHUNK_SHORTS 12288    // 384 n-rows * 32 j (plain, chunk-major)
#define MROWS 48              // gt rows per cheb block (4 g-slices), 3 exact m-tiles

typedef __attribute__((ext_vector_type(8))) short short8;
typedef __attribute__((ext_vector_type(4))) float floatx4;

static __device__ __forceinline__ unsigned short f2bf(float f) {
    unsigned int u = __float_as_uint(f);
    unsigned int r = (u + 0x7fffu + ((u >> 16) & 1u)) >> 16;  // RNE
    return (unsigned short)r;
}

// A-image index (shorts): [MROWS][KP], 16B slot XOR-swizzled by row pair
static __device__ __forceinline__ int xi(int m, int j) {
    int slot = (j >> 3) ^ ((m >> 1) & 3);
    return m * KP + slot * 8 + (j & 7);
}
// mix-kernel swizzle (row stride 384 B)
static __device__ __forceinline__ int swz(int n) {
    return ((n & 7) ^ ((n >> 3) & 7)) << 4;
}

// ---- setup: d^{-1/2} ----
__global__ void calc_dis(const float* __restrict__ adj, float* __restrict__ dis) {
    int i = blockIdx.x;
    const float* row = adj + (size_t)i * NND;
    float s = 0.f;
    for (int j = threadIdx.x; j < NND; j += 64) s += row[j];
    for (int o = 32; o; o >>= 1) s += __shfl_down(s, o);
    if (threadIdx.x == 0) dis[i] = (s > 0.f) ? rsqrtf(s) : 0.f;
}

// ---- setup: L chunk-major plain bf16 [c][n<384][32 j] (zero-padded) ----
__global__ void build_L2(const float* __restrict__ adj, const float* __restrict__ dis,
                         unsigned short* __restrict__ Lg2) {
    int s = blockIdx.x * 256 + threadIdx.x;
    if (s >= NC * CHUNK_SHORTS) return;
    int c = s / CHUNK_SHORTS, r = s - c * CHUNK_SHORTS;
    int n = r >> 5, w = r & 31;
    int j = c * 32 + w;
    float v = 0.f;
    if (n < NND && j < NND) {
        float a = adj[(size_t)n * NND + j];
        v = ((n == j) ? 1.f : 0.f) - dis[n] * a * dis[j];
    }
    Lg2[s] = f2bf(v);
}

// ---- setup: folded weights as swizzled bf16 image A[d][k], k=kind*64+c ----
__global__ void build_wswz(const float* __restrict__ W, unsigned short* __restrict__ wswz) {
    int idx = blockIdx.x * 256 + threadIdx.x;
    if (idx >= 64 * 192) return;
    int d = idx / 192, k = idx - d * 192;
    int kind = k >> 6, c = k & 63;
    float wv = W[kind * 4096 + c * 64 + d];
    float w;
    if (kind == 0)      w = wv - W[2 * 4096 + c * 64 + d];
    else if (kind == 1) w = wv;
    else                w = 2.f * wv;
    int byte = d * 384 + ((2 * k) ^ swz(d));
    wswz[byte >> 1] = f2bf(w);
}

// ---- Chebyshev double L-apply, register-persistent L.
// Block: 48 gt-rows (4 g-slices), 512 threads (8 waves). Wave w owns n-tiles
// {3w,3w+1,3w+2}; its L B-frags (33 x short8 = 132 VGPR) are loaded ONCE from
// the plain chunk-major image (fully coalesced 1KB/wave bursts) and persist
// across both GEMMs -> the k-loops have no barriers and no L traffic.
__global__ __launch_bounds__(512, 2) void cheb_mfma(
        const float* __restrict__ x,
        const unsigned short* __restrict__ Lg2,
        unsigned short* __restrict__ Yg,
        unsigned short* __restrict__ Zg) {
    __shared__ __align__(16) unsigned short Xs[MROWS * KP];   // 33792 B
    __shared__ __align__(16) unsigned short Ys[MROWS * KP];   // 33792 B

    const int tid = threadIdx.x;
    int bid = blockIdx.x;
    bid = (bid & 7) * 128 + (bid >> 3);       // XCD swizzle (1024 = 8*128)
    const int g0 = bid * 4;

    const int w  = tid >> 6;
    const int l  = tid & 63;
    const int lm = l & 15, lg = l >> 4;
    const int ap = (lm >> 1) & 3;             // A-slot XOR for row m=mt*16+lm

    // ---- persistent L fragments ----
    short8 Lf[3][NC];
    #pragma unroll
    for (int i = 0; i < 3; ++i) {
        const int nrow = (w * 3 + i) * 16 + lm;
        #pragma unroll
        for (int c = 0; c < NC; ++c)
            Lf[i][c] = *(const short8*)(Lg2 + (size_t)c * CHUNK_SHORTS + nrow * 32 + lg * 8);
    }

    // ---- stage X (and zero pad cols 325..351) ----
    for (int i = tid; i < MROWS * 27; i += 512) {
        int m = i / 27, j = 325 + (i - (i / 27) * 27);
        Xs[xi(m, j)] = 0;
    }
    const float4* xb = (const float4*)(x + (size_t)g0 * NT);
    for (int i = tid; i < 3900; i += 512) {
        float4 v = xb[i];
        int f = i * 4;
        int gl = f / NT;
        int rem = f - gl * NT;
        int j = rem / SEQ;
        int t0 = rem - j * SEQ;       // 0,4,8
        int m = gl * SEQ + t0;
        Xs[xi(m + 0, j)] = f2bf(v.x);
        Xs[xi(m + 1, j)] = f2bf(v.y);
        Xs[xi(m + 2, j)] = f2bf(v.z);
        Xs[xi(m + 3, j)] = f2bf(v.w);
    }
    __syncthreads();

    floatx4 acc[3][3];                // [mt][n-local]

    auto zero_acc = [&]() {
        #pragma unroll
        for (int a = 0; a < 3; ++a)
            #pragma unroll
            for (int b2 = 0; b2 < 3; ++b2) acc[a][b2] = (floatx4){0.f, 0.f, 0.f, 0.f};
    };

    auto gemm = [&](const unsigned short* Aimg) {
        #pragma unroll
        for (int c = 0; c < NC; ++c) {
            short8 af[3];
            #pragma unroll
            for (int mt = 0; mt < 3; ++mt) {
                int m = mt * 16 + lm;
                int slot = (c * 4 + lg) ^ ap;
                af[mt] = *(const short8*)&Aimg[m * KP + slot * 8];
            }
            #pragma unroll
            for (int i = 0; i < 3; ++i)
                #pragma unroll
                for (int mt = 0; mt < 3; ++mt)
                    acc[mt][i] = __builtin_amdgcn_mfma_f32_16x16x32_bf16(
                        af[mt], Lf[i][c], acc[mt][i], 0, 0, 0);
        }
    };

    auto store_acc = [&](unsigned short* img) {
        #pragma unroll
        for (int i = 0; i < 3; ++i) {
            int n = (w * 3 + i) * 16 + lm;
            if (n < KP) {
                #pragma unroll
                for (int mt = 0; mt < 3; ++mt)
                    #pragma unroll
                    for (int r = 0; r < 4; ++r)
                        img[xi(mt * 16 + lg * 4 + r, n)] = f2bf(acc[mt][i][r]);
            }
        }
    };

    auto copy_out = [&](const unsigned short* img, unsigned short* dst) {
        for (int i = tid; i < 1950 * 2; i += 512) {
            int gl = i / 975;
            int r2 = i - gl * 975;
            int n = r2 / 3;
            int tq = (r2 - n * 3) * 4;
            int m = gl * SEQ + tq;
            ushort4 u;
            u.x = img[xi(m + 0, n)];
            u.y = img[xi(m + 1, n)];
            u.z = img[xi(m + 2, n)];
            u.w = img[xi(m + 3, n)];
            *(ushort4*)&dst[(size_t)(g0 + gl) * NT + n * SEQ + tq] = u;
        }
    };

    // ---- GEMM1: Y = X * L ----
    zero_acc();
    gemm(Xs);
    store_acc(Ys);
    __syncthreads();                  // Ys complete; Xs reads all done
    copy_out(Ys, Yg);

    // ---- GEMM2: Z = Y * L ----
    zero_acc();
    gemm(Ys);
    store_acc(Xs);                    // reuse Xs as Z staging
    __syncthreads();
    copy_out(Xs, Zg);
}

// ---- Phase B: out = A(64x192) x B(192 x 96nt) per (b, nt-tile), MFMA ----
__global__ __launch_bounds__(256) void mix_mfma(
        const float* __restrict__ x,
        const unsigned short* __restrict__ Yg,
        const unsigned short* __restrict__ Zg,
        const unsigned short* __restrict__ wswz,
        const float* __restrict__ bias,
        float* __restrict__ out) {
    __shared__ unsigned short Bl[96 * 192];   // 36864 B swizzled [n][k]
    __shared__ unsigned short Al[64 * 192];   // 24576 B swizzled [d][k]
    const int tid = threadIdx.x;
    int lin = blockIdx.x;
    lin = (lin & 7) * 328 + (lin >> 3);       // XCD swizzle (2624 = 8*328)
    const int b = lin / 41;
    const int nt0 = (lin - b * 41) * 96;
    const bool tail = (nt0 + 96 > NT);

    for (int i = tid; i < 1536; i += 256)
        *(short8*)((char*)Al + i * 16) = *(const short8*)((const char*)wswz + i * 16);

    for (int i = tid; i < 768; i += 256) {
        int r = i / 12, ch = i - r * 12;
        int nt = nt0 + ch * 8;
        const float* sp = x + ((size_t)b * 64 + r) * NT + nt;
        float f[8];
        if (!tail || nt + 8 <= NT) {
            float4 v0 = *(const float4*)sp;
            float4 v1 = *(const float4*)(sp + 4);
            f[0] = v0.x; f[1] = v0.y; f[2] = v0.z; f[3] = v0.w;
            f[4] = v1.x; f[5] = v1.y; f[6] = v1.z; f[7] = v1.w;
        } else {
            #pragma unroll
            for (int jj = 0; jj < 8; ++jj) f[jj] = (nt + jj < NT) ? sp[jj] : 0.f;
        }
        int k2 = 2 * r;
        #pragma unroll
        for (int jj = 0; jj < 8; ++jj) {
            int n = ch * 8 + jj;
            *(unsigned short*)((char*)Bl + n * 384 + (k2 ^ swz(n))) = f2bf(f[jj]);
        }
    }
    for (int i = tid; i < 1536; i += 256) {
        int r = 64 + i / 12, ch = i % 12;
        int nt = nt0 + ch * 8;
        const unsigned short* base = (r < 128) ? Yg : Zg;
        const unsigned short* sp = base + ((size_t)b * 64 + (r & 63)) * NT + nt;
        unsigned short f[8];
        if (!tail || nt + 8 <= NT) {
            ushort4 v0 = *(const ushort4*)sp;
            ushort4 v1 = *(const ushort4*)(sp + 4);
            f[0] = v0.x; f[1] = v0.y; f[2] = v0.z; f[3] = v0.w;
            f[4] = v1.x; f[5] = v1.y; f[6] = v1.z; f[7] = v1.w;
        } else {
            #pragma unroll
            for (int jj = 0; jj < 8; ++jj) f[jj] = (nt + jj < NT) ? sp[jj] : (unsigned short)0;
        }
        int k2 = 2 * r;
        #pragma unroll
        for (int jj = 0; jj < 8; ++jj) {
            int n = ch * 8 + jj;
            *(unsigned short*)((char*)Bl + n * 384 + (k2 ^ swz(n))) = f[jj];
        }
    }
    __syncthreads();

    const int w = __builtin_amdgcn_readfirstlane(tid >> 6);
    const int l = tid & 63;
    const int lm = l & 15, lg = l >> 4;

    floatx4 acc[6];
    #pragma unroll
    for (int i = 0; i < 6; ++i) acc[i] = (floatx4){0.f, 0.f, 0.f, 0.f};

    const int arow = w * 16 + lm;
    const char* Ab = (const char*)Al + arow * 384;
    #pragma unroll
    for (int ks = 0; ks < 6; ++ks) {
        const int k2 = (ks * 32 + lg * 8) * 2;
        short8 a = *(const short8*)(Ab + (k2 ^ swz(arow)));
        #pragma unroll
        for (int ni = 0; ni < 6; ++ni) {
            int n = ni * 16 + lm;
            short8 bb = *(const short8*)((const char*)Bl + n * 384 + (k2 ^ swz(n)));
            acc[ni] = __builtin_amdgcn_mfma_f32_16x16x32_bf16(a, bb, acc[ni], 0, 0, 0);
        }
    }

    float br[4];
    #pragma unroll
    for (int j = 0; j < 4; ++j) br[j] = bias[w * 16 + lg * 4 + j];
    #pragma unroll
    for (int ni = 0; ni < 6; ++ni) {
        int nt = nt0 + ni * 16 + lm;
        if (nt < NT) {
            float* op = out + ((size_t)b * 64 + w * 16 + lg * 4) * NT + nt;
            #pragma unroll
            for (int j = 0; j < 4; ++j) op[(size_t)j * NT] = acc[ni][j] + br[j];
        }
    }
}

extern "C" void kernel_launch(void* const* d_in, const int* in_sizes, int n_in,
                              void* d_out, int out_size, void* d_ws, size_t ws_size,
                              hipStream_t stream) {
    const float* x   = (const float*)d_in[0];
    const float* adj = (const float*)d_in[1];
    const float* W   = (const float*)d_in[2];
    const float* b   = (const float*)d_in[3];
    float* out = (float*)d_out;

    char* ws = (char*)d_ws;
    // layout (bytes):
    //   0        : dis   (325 f32, pad 1312)
    //   1312     : Lg2   (11*12288 bf16 = 270336)
    //   271648   : wswz  (12288 bf16 = 24576)
    //   296224   : Y     (4096*3900 bf16 = 31948800)
    //   32245024 : Z     (31948800) -> end 64193824 (~61.2 MiB)
    float* dis           = (float*)(ws + 0);
    unsigned short* Lg2  = (unsigned short*)(ws + 1312);
    unsigned short* wswz = (unsigned short*)(ws + 271648);
    unsigned short* Yg   = (unsigned short*)(ws + 296224);
    unsigned short* Zg   = (unsigned short*)(ws + 32245024);

    calc_dis<<<NND, 64, 0, stream>>>(adj, dis);
    build_L2<<<(NC * CHUNK_SHORTS + 255) / 256, 256, 0, stream>>>(adj, dis, Lg2);
    build_wswz<<<48, 256, 0, stream>>>(W, wswz);
    cheb_mfma<<<1024, 512, 0, stream>>>(x, Lg2, Yg, Zg);
    mix_mfma<<<2624, 256, 0, stream>>>(x, Yg, Zg, wswz, b, out);
}

// Round 6
// 125.616 us; speedup vs baseline: 1.3120x; 1.0140x over previous
//
#include <hip/hip_runtime.h>
#include <hip/hip_bf16.h>

#define NND   325
#define SEQ   12
#define NT    3900            // 325*12
#define KP    352             // padded j (11 chunks of 32)
#define NC    11              // k-chunks of 32
#define CHUNK_SHORTS 12288    // 384 n-rows * 32 j (plain, chunk-major)
#define MROWS 48              // gt rows per cheb block (4 g-slices), 3 exact m-tiles
#define NTILE 22              // n-tiles of 16 (352/16)

typedef __attribute__((ext_vector_type(8))) short short8;
typedef __attribute__((ext_vector_type(4))) float floatx4;

static __device__ __forceinline__ unsigned short f2bf(float f) {
    unsigned int u = __float_as_uint(f);
    unsigned int r = (u + 0x7fffu + ((u >> 16) & 1u)) >> 16;  // RNE
    return (unsigned short)r;
}

// A-image index (shorts): [MROWS][KP], 16B slot XOR-swizzled by row pair
static __device__ __forceinline__ int xi(int m, int j) {
    int slot = (j >> 3) ^ ((m >> 1) & 3);
    return m * KP + slot * 8 + (j & 7);
}
// mix-kernel swizzle (row stride 384 B)
static __device__ __forceinline__ int swz(int n) {
    return ((n & 7) ^ ((n >> 3) & 7)) << 4;
}

// ---- setup: d^{-1/2} ----
__global__ void calc_dis(const float* __restrict__ adj, float* __restrict__ dis) {
    int i = blockIdx.x;
    const float* row = adj + (size_t)i * NND;
    float s = 0.f;
    for (int j = threadIdx.x; j < NND; j += 64) s += row[j];
    for (int o = 32; o; o >>= 1) s += __shfl_down(s, o);
    if (threadIdx.x == 0) dis[i] = (s > 0.f) ? rsqrtf(s) : 0.f;
}

// ---- setup: L chunk-major plain bf16 [c][n<384][32 j] (zero-padded) ----
__global__ void build_L2(const float* __restrict__ adj, const float* __restrict__ dis,
                         unsigned short* __restrict__ Lg2) {
    int s = blockIdx.x * 256 + threadIdx.x;
    if (s >= NC * CHUNK_SHORTS) return;
    int c = s / CHUNK_SHORTS, r = s - c * CHUNK_SHORTS;
    int n = r >> 5, w = r & 31;
    int j = c * 32 + w;
    float v = 0.f;
    if (n < NND && j < NND) {
        float a = adj[(size_t)n * NND + j];
        v = ((n == j) ? 1.f : 0.f) - dis[n] * a * dis[j];
    }
    Lg2[s] = f2bf(v);
}

// ---- setup: folded weights as swizzled bf16 image A[d][k], k=kind*64+c ----
__global__ void build_wswz(const float* __restrict__ W, unsigned short* __restrict__ wswz) {
    int idx = blockIdx.x * 256 + threadIdx.x;
    if (idx >= 64 * 192) return;
    int d = idx / 192, k = idx - d * 192;
    int kind = k >> 6, c = k & 63;
    float wv = W[kind * 4096 + c * 64 + d];
    float w;
    if (kind == 0)      w = wv - W[2 * 4096 + c * 64 + d];
    else if (kind == 1) w = wv;
    else                w = 2.f * wv;
    int byte = d * 384 + ((2 * k) ^ swz(d));
    wswz[byte >> 1] = f2bf(w);
}

// ---- Chebyshev double L-apply, streamed-L version.
// Block: 48 gt-rows (4 g-slices), 512 threads (8 waves), 66 KB LDS, <=128 VGPR
// -> 2 blocks/CU, 4 waves/SIMD. Wave w owns n-tiles {3w,3w+1,3w+2} (ti<22).
// L B-frags are STREAMED from the chunk-major global image (L2-hot, 1KB
// coalesced bursts) inside a barrier-free k-loop: per chunk, 3 global loads +
// 3 ds_read_b128 + 9 MFMAs. No L residency in LDS or persistent registers.
__global__ __launch_bounds__(512, 4) void cheb_mfma(
        const float* __restrict__ x,
        const unsigned short* __restrict__ Lg2,
        unsigned short* __restrict__ Yg,
        unsigned short* __restrict__ Zg) {
    __shared__ __align__(16) unsigned short Xs[MROWS * KP];   // 33792 B
    __shared__ __align__(16) unsigned short Ys[MROWS * KP];   // 33792 B

    const int tid = threadIdx.x;
    int bid = blockIdx.x;
    bid = (bid & 7) * 128 + (bid >> 3);       // XCD swizzle (1024 = 8*128)
    const int g0 = bid * 4;

    const int w  = tid >> 6;
    const int l  = tid & 63;
    const int lm = l & 15, lg = l >> 4;
    const int ap = (lm >> 1) & 3;             // A-slot XOR for row m=mt*16+lm

    // per-wave L fragment base addresses (lane-dependent), tiles 3w..3w+2
    const unsigned short* lp[3];
    #pragma unroll
    for (int i = 0; i < 3; ++i) {
        int ti = w * 3 + i;
        int nrow = ti * 16 + lm;
        lp[i] = Lg2 + (size_t)nrow * 32 + lg * 8;   // + c*CHUNK_SHORTS per chunk
    }
    const int nown = (w * 3 + 2 < NTILE) ? 3 : (NTILE - w * 3 < 0 ? 0 : NTILE - w * 3);

    // ---- stage X (and zero pad cols 325..351) ----
    for (int i = tid; i < MROWS * 27; i += 512) {
        int m = i / 27, j = 325 + (i - (i / 27) * 27);
        Xs[xi(m, j)] = 0;
    }
    const float4* xb = (const float4*)(x + (size_t)g0 * NT);
    for (int i = tid; i < 3900; i += 512) {
        float4 v = xb[i];
        int f = i * 4;
        int gl = f / NT;
        int rem = f - gl * NT;
        int j = rem / SEQ;
        int t0 = rem - j * SEQ;       // 0,4,8
        int m = gl * SEQ + t0;
        Xs[xi(m + 0, j)] = f2bf(v.x);
        Xs[xi(m + 1, j)] = f2bf(v.y);
        Xs[xi(m + 2, j)] = f2bf(v.z);
        Xs[xi(m + 3, j)] = f2bf(v.w);
    }
    __syncthreads();

    floatx4 acc[3][3];                // [mt][n-local]

    auto zero_acc = [&]() {
        #pragma unroll
        for (int a = 0; a < 3; ++a)
            #pragma unroll
            for (int b2 = 0; b2 < 3; ++b2) acc[a][b2] = (floatx4){0.f, 0.f, 0.f, 0.f};
    };

    auto gemm = [&](const unsigned short* Aimg) {
        #pragma unroll
        for (int c = 0; c < NC; ++c) {
            short8 bf[3];
            #pragma unroll
            for (int i = 0; i < 3; ++i)
                if (i < nown)
                    bf[i] = *(const short8*)(lp[i] + (size_t)c * CHUNK_SHORTS);
            short8 af[3];
            #pragma unroll
            for (int mt = 0; mt < 3; ++mt) {
                int m = mt * 16 + lm;
                int slot = (c * 4 + lg) ^ ap;
                af[mt] = *(const short8*)&Aimg[m * KP + slot * 8];
            }
            #pragma unroll
            for (int i = 0; i < 3; ++i)
                if (i < nown)
                    #pragma unroll
                    for (int mt = 0; mt < 3; ++mt)
                        acc[mt][i] = __builtin_amdgcn_mfma_f32_16x16x32_bf16(
                            af[mt], bf[i], acc[mt][i], 0, 0, 0);
        }
    };

    auto store_acc = [&](unsigned short* img) {
        #pragma unroll
        for (int i = 0; i < 3; ++i) {
            if (i < nown) {
                int n = (w * 3 + i) * 16 + lm;
                #pragma unroll
                for (int mt = 0; mt < 3; ++mt)
                    #pragma unroll
                    for (int r = 0; r < 4; ++r)
                        img[xi(mt * 16 + lg * 4 + r, n)] = f2bf(acc[mt][i][r]);
            }
        }
    };

    auto copy_out = [&](const unsigned short* img, unsigned short* dst) {
        for (int i = tid; i < 1950 * 2; i += 512) {
            int gl = i / 975;
            int r2 = i - gl * 975;
            int n = r2 / 3;
            int tq = (r2 - n * 3) * 4;
            int m = gl * SEQ + tq;
            ushort4 u;
            u.x = img[xi(m + 0, n)];
            u.y = img[xi(m + 1, n)];
            u.z = img[xi(m + 2, n)];
            u.w = img[xi(m + 3, n)];
            *(ushort4*)&dst[(size_t)(g0 + gl) * NT + n * SEQ + tq] = u;
        }
    };

    // ---- GEMM1: Y = X * L ----
    zero_acc();
    gemm(Xs);
    store_acc(Ys);
    __syncthreads();                  // Ys complete; all Xs reads done
    copy_out(Ys, Yg);

    // ---- GEMM2: Z = Y * L ----
    zero_acc();
    gemm(Ys);
    store_acc(Xs);                    // reuse Xs as Z staging
    __syncthreads();
    copy_out(Xs, Zg);
}

// ---- Phase B: out = A(64x192) x B(192 x 96nt) per (b, nt-tile), MFMA ----
__global__ __launch_bounds__(256) void mix_mfma(
        const float* __restrict__ x,
        const unsigned short* __restrict__ Yg,
        const unsigned short* __restrict__ Zg,
        const unsigned short* __restrict__ wswz,
        const float* __restrict__ bias,
        float* __restrict__ out) {
    __shared__ unsigned short Bl[96 * 192];   // 36864 B swizzled [n][k]
    __shared__ unsigned short Al[64 * 192];   // 24576 B swizzled [d][k]
    const int tid = threadIdx.x;
    int lin = blockIdx.x;
    lin = (lin & 7) * 328 + (lin >> 3);       // XCD swizzle (2624 = 8*328)
    const int b = lin / 41;
    const int nt0 = (lin - b * 41) * 96;
    const bool tail = (nt0 + 96 > NT);

    for (int i = tid; i < 1536; i += 256)
        *(short8*)((char*)Al + i * 16) = *(const short8*)((const char*)wswz + i * 16);

    for (int i = tid; i < 768; i += 256) {
        int r = i / 12, ch = i - r * 12;
        int nt = nt0 + ch * 8;
        const float* sp = x + ((size_t)b * 64 + r) * NT + nt;
        float f[8];
        if (!tail || nt + 8 <= NT) {
            float4 v0 = *(const float4*)sp;
            float4 v1 = *(const float4*)(sp + 4);
            f[0] = v0.x; f[1] = v0.y; f[2] = v0.z; f[3] = v0.w;
            f[4] = v1.x; f[5] = v1.y; f[6] = v1.z; f[7] = v1.w;
        } else {
            #pragma unroll
            for (int jj = 0; jj < 8; ++jj) f[jj] = (nt + jj < NT) ? sp[jj] : 0.f;
        }
        int k2 = 2 * r;
        #pragma unroll
        for (int jj = 0; jj < 8; ++jj) {
            int n = ch * 8 + jj;
            *(unsigned short*)((char*)Bl + n * 384 + (k2 ^ swz(n))) = f2bf(f[jj]);
        }
    }
    for (int i = tid; i < 1536; i += 256) {
        int r = 64 + i / 12, ch = i % 12;
        int nt = nt0 + ch * 8;
        const unsigned short* base = (r < 128) ? Yg : Zg;
        const unsigned short* sp = base + ((size_t)b * 64 + (r & 63)) * NT + nt;
        unsigned short f[8];
        if (!tail || nt + 8 <= NT) {
            ushort4 v0 = *(const ushort4*)sp;
            ushort4 v1 = *(const ushort4*)(sp + 4);
            f[0] = v0.x; f[1] = v0.y; f[2] = v0.z; f[3] = v0.w;
            f[4] = v1.x; f[5] = v1.y; f[6] = v1.z; f[7] = v1.w;
        } else {
            #pragma unroll
            for (int jj = 0; jj < 8; ++jj) f[jj] = (nt + jj < NT) ? sp[jj] : (unsigned short)0;
        }
        int k2 = 2 * r;
        #pragma unroll
        for (int jj = 0; jj < 8; ++jj) {
            int n = ch * 8 + jj;
            *(unsigned short*)((char*)Bl + n * 384 + (k2 ^ swz(n))) = f[jj];
        }
    }
    __syncthreads();

    const int w = __builtin_amdgcn_readfirstlane(tid >> 6);
    const int l = tid & 63;
    const int lm = l & 15, lg = l >> 4;

    floatx4 acc[6];
    #pragma unroll
    for (int i = 0; i < 6; ++i) acc[i] = (floatx4){0.f, 0.f, 0.f, 0.f};

    const int arow = w * 16 + lm;
    const char* Ab = (const char*)Al + arow * 384;
    #pragma unroll
    for (int ks = 0; ks < 6; ++ks) {
        const int k2 = (ks * 32 + lg * 8) * 2;
        short8 a = *(const short8*)(Ab + (k2 ^ swz(arow)));
        #pragma unroll
        for (int ni = 0; ni < 6; ++ni) {
            int n = ni * 16 + lm;
            short8 bb = *(const short8*)((const char*)Bl + n * 384 + (k2 ^ swz(n)));
            acc[ni] = __builtin_amdgcn_mfma_f32_16x16x32_bf16(a, bb, acc[ni], 0, 0, 0);
        }
    }

    float br[4];
    #pragma unroll
    for (int j = 0; j < 4; ++j) br[j] = bias[w * 16 + lg * 4 + j];
    #pragma unroll
    for (int ni = 0; ni < 6; ++ni) {
        int nt = nt0 + ni * 16 + lm;
        if (nt < NT) {
            float* op = out + ((size_t)b * 64 + w * 16 + lg * 4) * NT + nt;
            #pragma unroll
            for (int j = 0; j < 4; ++j) op[(size_t)j * NT] = acc[ni][j] + br[j];
        }
    }
}

extern "C" void kernel_launch(void* const* d_in, const int* in_sizes, int n_in,
                              void* d_out, int out_size, void* d_ws, size_t ws_size,
                              hipStream_t stream) {
    const float* x   = (const float*)d_in[0];
    const float* adj = (const float*)d_in[1];
    const float* W   = (const float*)d_in[2];
    const float* b   = (const float*)d_in[3];
    float* out = (float*)d_out;

    char* ws = (char*)d_ws;
    // layout (bytes):
    //   0        : dis   (325 f32, pad 1312)
    //   1312     : Lg2   (11*12288 bf16 = 270336)
    //   271648   : wswz  (12288 bf16 = 24576)
    //   296224   : Y     (4096*3900 bf16 = 31948800)
    //   32245024 : Z     (31948800) -> end 64193824 (~61.2 MiB)
    float* dis           = (float*)(ws + 0);
    unsigned short* Lg2  = (unsigned short*)(ws + 1312);
    unsigned short* wswz = (unsigned short*)(ws + 271648);
    unsigned short* Yg   = (unsigned short*)(ws + 296224);
    unsigned short* Zg   = (unsigned short*)(ws + 32245024);

    calc_dis<<<NND, 64, 0, stream>>>(adj, dis);
    build_L2<<<(NC * CHUNK_SHORTS + 255) / 256, 256, 0, stream>>>(adj, dis, Lg2);
    build_wswz<<<48, 256, 0, stream>>>(W, wswz);
    cheb_mfma<<<1024, 512, 0, stream>>>(x, Lg2, Yg, Zg);
    mix_mfma<<<2624, 256, 0, stream>>>(x, Yg, Zg, wswz, b, out);
}